// Round 1
// 231.976 us; speedup vs baseline: 1.3045x; 1.3045x over previous
//
#include <hip/hip_runtime.h>

// CRF NLL on MI355X, round 3: DPP team-reduce + deferred (every-4-step) rescale.
// Latency-bound sequential scan (1 block/batch-elem, ~512 dependent steps).
// Changes vs round 2:
//  (1) 8-lane team reduction done with DPP adds (quad_perm xor1, quad_perm
//      xor2, row_half_mirror) instead of __shfl_xor -> ds_bpermute: 3 VALU-
//      latency hops instead of 3 LDS-pipe round trips on the critical path.
//  (2) Rescale deferred to once per 4-step group: divide by the *current*
//      u_t[0] (read straight from the live buffer) and S += log(c) only on
//      k==3 steps. Exact bookkeeping; removes cbox entirely and takes the
//      c-broadcast + rcp + logf off the critical path on 3/4 steps.
//      Headroom: un-rescaled growth ~e^5.3/step -> peak ~e^21..e^30 << e^88.

#define BB   128
#define TT   512
#define CC   128
#define NTHR 512
#define PF   4

typedef float v2f __attribute__((ext_vector_type(2)));

__device__ __forceinline__ void bar_nodrain() {
    // LDS-visibility barrier that does NOT drain vmcnt (global prefetch stays
    // in flight). "memory" clobber stops compiler reordering across it.
    asm volatile("s_waitcnt lgkmcnt(0)\n\ts_barrier" ::: "memory");
}

template<int CTRL>
__device__ __forceinline__ float dpp_xadd(float x) {
    const int y = __builtin_amdgcn_update_dpp(0, __float_as_int(x), CTRL, 0xF, 0xF, true);
    return x + __int_as_float(y);
}

// Sum across each aligned group of 8 lanes (team) at VALU speed.
__device__ __forceinline__ float red8(float x) {
    x = dpp_xadd<0xB1>(x);    // quad_perm(1,0,3,2): + lane^1
    x = dpp_xadd<0x4E>(x);    // quad_perm(2,3,0,1): + lane^2
    x = dpp_xadd<0x141>(x);   // row_half_mirror:    + lane^4 within each 8
    return x;
}

__global__ __launch_bounds__(NTHR) void crf_fused(
    const float* __restrict__ feats,
    const int*   __restrict__ mask,
    const int*   __restrict__ tags,
    const float* __restrict__ trans,
    float*       __restrict__ acc)   // acc[0] += forward, acc[1] += gold score
{
    const int b   = blockIdx.x;
    const int tid = threadIdx.x;
    const int jp  = tid >> 3;        // team: columns 2jp, 2jp+1
    const int sub = tid & 7;         // 16-row i-slice
    const int j0  = jp * 2;
    const int j1  = j0 + 1;
    const int wid = tid >> 6;

    __shared__ __align__(16) float buf[2][CC];  // double-buffered u vector
    __shared__ float wred[8];

    // ---- sequence length (contiguous prefix mask; tid spans T exactly) ----
    const int myM = mask[b * TT + tid];
    const int len = __syncthreads_count(myM);

    // ---- gold-path score (once; off the scan's critical path) ----
    {
        float sc = 0.0f;
        if (myM) {
            const int tg = tags[b * TT + tid];
            sc += feats[((size_t)(b * TT + tid)) * CC + tg];
            sc += (tid == 0) ? trans[(CC - 2) * CC + tg]
                             : trans[tags[b * TT + tid - 1] * CC + tg];
            const int nm = (tid == TT - 1) ? 0 : mask[b * TT + tid + 1];
            if (!nm) sc += trans[tg * CC + (CC - 1)];
        }
        #pragma unroll
        for (int o = 1; o <= 32; o <<= 1) sc += __shfl_xor(sc, o);
        if ((tid & 63) == 0) wred[wid] = sc;
        __syncthreads();
        if (tid == 0) {
            float s = 0.0f;
            #pragma unroll
            for (int k = 0; k < 8; ++k) s += wred[k];
            atomicAdd(&acc[1], s);
        }
        // wred re-used only after the post-loop __syncthreads().
    }

    // ---- E fragments, chunk order swizzled so each wave's 8 distinct 16B
    //      chunks hit 8 distinct bank quads (conflict-free) ----
    const int s2 = sub >> 1;
    int kkA[4];
    v2f E0v[8], E1v[8];
    #pragma unroll
    for (int k = 0; k < 4; ++k) {
        const int kk = (k + s2) & 3;
        kkA[k] = kk;
        const int r = sub * 16 + kk * 4;
        #pragma unroll
        for (int m = 0; m < 2; ++m) {
            const int r0 = r + 2 * m;
            const float2 ta = *(const float2*)&trans[(size_t)(r0    ) * CC + j0];
            const float2 tb = *(const float2*)&trans[(size_t)(r0 + 1) * CC + j0];
            v2f e0, e1;
            e0.x = __expf(ta.x); e0.y = __expf(tb.x);
            e1.x = __expf(ta.y); e1.y = __expf(tb.y);
            E0v[2 * k + m] = e0;
            E1v[2 * k + m] = e1;
        }
    }
    // terminal transition-to-STOP factors
    const float Es0 = __expf(trans[(size_t)j0 * CC + (CC - 1)]);
    const float Es1 = __expf(trans[(size_t)j1 * CC + (CC - 1)]);

    // ---- init: u_0 = 1 at START(126), 0 elsewhere ----
    if (tid < CC) buf[0][tid] = (tid == CC - 2) ? 1.0f : 0.0f;

    // ---- feats prefetch (PF deep, rotating registers) ----
    const float* fb = feats + (size_t)b * TT * CC;
    float2 fx[PF];
    #pragma unroll
    for (int k = 0; k < PF; ++k)
        fx[k] = *(const float2*)&fb[(size_t)k * CC + j0];

    const float* pb0 = &buf[0][sub * 16];
    const float* pb1 = &buf[1][sub * 16];

    float S = 0.0f;                          // sum of applied log(c)
    const int lenUp = (len + 3) & ~3;

    for (int tc = 0; tc < lenUp; tc += 4) {
        #pragma unroll
        for (int k = 0; k < 4; ++k) {
            const int t   = tc + k;
            const int par = k & 1;           // == t & 1
            bar_nodrain();                   // buf[par] now visible
            const float4* q = (const float4*)(par ? pb1 : pb0);
            float c = 1.0f;
            if (k == 3) c = buf[1][0];       // current u_t[0] (par==1); broadcast read

            v2f a0 = {0.f, 0.f}, a1 = {0.f, 0.f};
            v2f b0 = {0.f, 0.f}, b1 = {0.f, 0.f};
            #pragma unroll
            for (int kq = 0; kq < 4; ++kq) {
                const float4 P = q[kkA[kq]];
                v2f P01; P01.x = P.x; P01.y = P.y;
                v2f P23; P23.x = P.z; P23.y = P.w;
                a0 = __builtin_elementwise_fma(E0v[2 * kq],     P01, a0);
                a1 = __builtin_elementwise_fma(E0v[2 * kq + 1], P23, a1);
                b0 = __builtin_elementwise_fma(E1v[2 * kq],     P01, b0);
                b1 = __builtin_elementwise_fma(E1v[2 * kq + 1], P23, b1);
            }
            a0 += a1; b0 += b1;
            float s0 = red8(a0.x + a0.y);
            float s1 = red8(b0.x + b0.y);

            // exps stay inside step k: keeps the global prefetch a full
            // PF=4 steps ahead of consumption (hoisting to group top would
            // shrink the effective prefetch distance to ~1 step).
            const float e0f = __expf(fx[k].x);
            const float e1f = __expf(fx[k].y);
            float v0, v1;
            if (k == 3) {
                const float rinv = __builtin_amdgcn_rcpf(c);
                v0 = e0f * s0 * rinv;
                v1 = e1f * s1 * rinv;
            } else {
                v0 = e0f * s0;
                v1 = e1f * s1;
            }

            // prefetch feats for step t+PF (clamped; identical work each call)
            int tn = t + PF;
            tn = (tn < TT) ? tn : (TT - 1);
            fx[k] = *(const float2*)&fb[(size_t)tn * CC + j0];

            if (t < len) {                   // uniform branch
                if (k == 3) S += __logf(c);  // record exactly what was divided
                if (sub == 0) {
                    float2 w2; w2.x = v0; w2.y = v1;
                    *(float2*)&buf[par ^ 1][j0] = w2;
                }
            }
            // steps t >= len: no writes -> state frozen (padding is a no-op)
        }
    }

    // ---- terminal: log(sum_j u_len[j] * exp(trans[j][STOP])) + S ----
    __syncthreads();                         // full barrier: buf/wred safe
    const float2 uu = *(const float2*)&buf[len & 1][j0];
    float z = (sub == 0) ? (uu.x * Es0 + uu.y * Es1) : 0.0f;
    #pragma unroll
    for (int o = 1; o <= 32; o <<= 1) z += __shfl_xor(z, o);
    if ((tid & 63) == 0) wred[wid] = z;
    __syncthreads();
    if (tid == 0) {
        float s = 0.0f;
        #pragma unroll
        for (int k = 0; k < 8; ++k) s += wred[k];
        atomicAdd(&acc[0], __logf(s) + S);
    }
}

__global__ void crf_final(const float* __restrict__ acc, float* __restrict__ out)
{
    out[0] = (acc[0] - acc[1]) * (1.0f / (float)BB);
}

extern "C" void kernel_launch(void* const* d_in, const int* in_sizes, int n_in,
                              void* d_out, int out_size, void* d_ws, size_t ws_size,
                              hipStream_t stream)
{
    const float* feats = (const float*)d_in[0];
    const int*   mask  = (const int*)d_in[1];
    const int*   tags  = (const int*)d_in[2];
    const float* trans = (const float*)d_in[3];
    float* out = (float*)d_out;
    float* acc = (float*)d_ws;

    hipMemsetAsync(acc, 0, 2 * sizeof(float), stream);
    crf_fused<<<BB, NTHR, 0, stream>>>(feats, mask, tags, trans, acc);
    crf_final<<<1, 1, 0, stream>>>(acc, out);
}